// Round 3
// baseline (743.355 us; speedup 1.0000x reference)
//
#include <hip/hip_runtime.h>
#include <hip/hip_bf16.h>

// MultiHeadedAttn: B=4 T=2048 D=512 H=8 DK=64
// out = (x @ Wo^T + bo)  where x = softmax(QK^T/8) V  per head
// plus sigmoid(scores) (B,H,T,T) = 536MB fp32 -> write-bound overall.
// R2: resubmit (GPU acquisition timed out R0/R1; kernel has never run).

#define DEV static __device__ __forceinline__

typedef __attribute__((ext_vector_type(8))) short bf16x8;
typedef __attribute__((ext_vector_type(4))) float f32x4;

constexpr int BB = 4, TT = 2048, DD = 512, HH = 8, DKK = 64;

DEV short f2bf(float f) {
  unsigned u = __float_as_uint(f);
  unsigned r = 0x7fffu + ((u >> 16) & 1u);  // RNE
  return (short)((u + r) >> 16);
}

// ---------------------------------------------------------------------------
// GEMM: C[M][512] = A[M][512] @ W[512][512]^T + bias   (A fp32 or bf16)
// 128x128 tile, BK=64, 4 waves (2x2), wave tile 64x64 = 4x4 mfma 16x16x32.
// ---------------------------------------------------------------------------
template <bool A_IS_BF16, bool OUT_BF16>
DEV void gemm_body(const void* Av, const float* __restrict__ W,
                   const float* __restrict__ bias, void* Cv,
                   short (*As)[72], short (*Ws)[72]) {
  const int tid = threadIdx.x;
  const int lane = tid & 63;
  const int wv = tid >> 6;
  const int wm = wv >> 1, wn = wv & 1;
  const int m0 = blockIdx.x * 128;
  const int n0 = blockIdx.y * 128;
  const int K = 512;
  const int l15 = lane & 15, l4 = lane >> 4;

  f32x4 acc[4][4] = {};

  for (int kk = 0; kk < K; kk += 64) {
    __syncthreads();
    // stage A tile 128x64 -> bf16 LDS (pad 72 keeps bank aliasing <=2-way)
    if constexpr (!A_IS_BF16) {
      const float* A = (const float*)Av;
#pragma unroll
      for (int r2 = 0; r2 < 8; ++r2) {
        int idx = r2 * 256 + tid;
        int row = idx >> 4, c4 = idx & 15;
        float4 v = *(const float4*)&A[(size_t)(m0 + row) * K + kk + c4 * 4];
        union { short h[4]; unsigned long long u; } cv;
        cv.h[0] = f2bf(v.x); cv.h[1] = f2bf(v.y);
        cv.h[2] = f2bf(v.z); cv.h[3] = f2bf(v.w);
        *(unsigned long long*)&As[row][c4 * 4] = cv.u;
      }
    } else {
      const short* A = (const short*)Av;
#pragma unroll
      for (int r2 = 0; r2 < 4; ++r2) {
        int idx = r2 * 256 + tid;
        int row = idx >> 3, c8 = idx & 7;
        *(bf16x8*)&As[row][c8 * 8] =
            *(const bf16x8*)&A[(size_t)(m0 + row) * K + kk + c8 * 8];
      }
    }
    // stage W tile 128x64 (rows n0..n0+128), fp32 -> bf16
#pragma unroll
    for (int r2 = 0; r2 < 8; ++r2) {
      int idx = r2 * 256 + tid;
      int row = idx >> 4, c4 = idx & 15;
      float4 v = *(const float4*)&W[(size_t)(n0 + row) * K + kk + c4 * 4];
      union { short h[4]; unsigned long long u; } cv;
      cv.h[0] = f2bf(v.x); cv.h[1] = f2bf(v.y);
      cv.h[2] = f2bf(v.z); cv.h[3] = f2bf(v.w);
      *(unsigned long long*)&Ws[row][c4 * 4] = cv.u;
    }
    __syncthreads();

#pragma unroll
    for (int kf = 0; kf < 2; ++kf) {
      bf16x8 af[4], bf[4];
#pragma unroll
      for (int i = 0; i < 4; ++i)
        af[i] = *(const bf16x8*)&As[wm * 64 + i * 16 + l15][kf * 32 + l4 * 8];
#pragma unroll
      for (int j = 0; j < 4; ++j)
        bf[j] = *(const bf16x8*)&Ws[wn * 64 + j * 16 + l15][kf * 32 + l4 * 8];
#pragma unroll
      for (int i = 0; i < 4; ++i)
#pragma unroll
        for (int j = 0; j < 4; ++j)
          acc[i][j] = __builtin_amdgcn_mfma_f32_16x16x32_bf16(af[i], bf[j],
                                                              acc[i][j], 0, 0, 0);
    }
  }

  // epilogue: C layout col=lane&15, row=(lane>>4)*4+reg  [m89-verified]
#pragma unroll
  for (int i = 0; i < 4; ++i) {
    int rbase = m0 + wm * 64 + i * 16 + l4 * 4;
#pragma unroll
    for (int j = 0; j < 4; ++j) {
      int col = n0 + wn * 64 + j * 16 + l15;
      float bv = bias[col];
#pragma unroll
      for (int rg = 0; rg < 4; ++rg) {
        float val = acc[i][j][rg] + bv;
        size_t off = (size_t)(rbase + rg) * 512 + col;
        if constexpr (OUT_BF16)
          ((short*)Cv)[off] = f2bf(val);
        else
          ((float*)Cv)[off] = val;
      }
    }
  }
}

struct ProjArgs {
  const float* A[3];
  const float* W[3];
  const float* bias[3];
  short* C[3];
};

__global__ __launch_bounds__(256)
void proj_gemm_kernel(ProjArgs args) {
  __shared__ short As[128][72];
  __shared__ short Ws[128][72];
  const int z = blockIdx.z;
  gemm_body<false, true>(args.A[z], args.W[z], args.bias[z], args.C[z], As, Ws);
}

__global__ __launch_bounds__(256)
void out_gemm_kernel(const short* __restrict__ X, const float* __restrict__ W,
                     const float* __restrict__ bias, float* __restrict__ C) {
  __shared__ short As[128][72];
  __shared__ short Ws[128][72];
  gemm_body<true, false>(X, W, bias, C, As, Ws);
}

// ---------------------------------------------------------------------------
// Flash attention + sigmoid dump.
// Block: 256 thr (4 waves). Each block: one (b,h), 64 q-rows; wave owns 16.
// KV tiles of 64. S via mfma(Q,K), sigmoid->global, online softmax,
// P->LDS (C-frag -> A-frag relayout), O += P*V via mfma with V^T in LDS.
// ---------------------------------------------------------------------------
__global__ __launch_bounds__(256)
void attn_kernel(const short* __restrict__ Qp, const short* __restrict__ Kp,
                 const short* __restrict__ Vp, const int* __restrict__ mask,
                 float* __restrict__ sig, short* __restrict__ Xout) {
  __shared__ short Kt[64][72];      // [kv][d] row-major
  __shared__ short Vt[64][72];      // [d][kv] transposed
  __shared__ short Pl[4][16][72];   // per-wave P tile [qrow][kv]

  const int tid = threadIdx.x;
  const int lane = tid & 63;
  const int w = tid >> 6;
  const int q0 = blockIdx.x * 64;
  const int h = blockIdx.y;
  const int b = blockIdx.z;
  const int l15 = lane & 15, l4 = lane >> 4;

  // Q fragments (A-frag: row=lane&15, k contiguous 8 at (lane>>4)*8)
  bf16x8 qf[2];
  {
    const short* qptr = &Qp[((size_t)b * TT + q0 + w * 16 + l15) * DD + h * DKK];
    qf[0] = *(const bf16x8*)&qptr[l4 * 8];
    qf[1] = *(const bf16x8*)&qptr[32 + l4 * 8];
  }

  float m_r[4], l_r[4];
  f32x4 accO[4] = {};
#pragma unroll
  for (int i = 0; i < 4; ++i) { m_r[i] = -INFINITY; l_r[i] = 0.f; }

  for (int kv0 = 0; kv0 < TT; kv0 += 64) {
    __syncthreads();
    // stage K row-major (coalesced 128B rows)
#pragma unroll
    for (int r2 = 0; r2 < 2; ++r2) {
      int idx = r2 * 256 + tid;
      int kr = idx >> 3, c8 = idx & 7;
      *(bf16x8*)&Kt[kr][c8 * 8] =
          *(const bf16x8*)&Kp[((size_t)b * TT + kv0 + kr) * DD + h * DKK + c8 * 8];
    }
    // stage V transposed: lanes sweep kv so LDS writes are stride-1 (no conflict)
#pragma unroll
    for (int r2 = 0; r2 < 2; ++r2) {
      int idx = r2 * 256 + tid;
      int kv = idx & 63, c8 = idx >> 6;
      bf16x8 vv = *(const bf16x8*)&Vp[((size_t)b * TT + kv0 + kv) * DD + h * DKK + c8 * 8];
#pragma unroll
      for (int i = 0; i < 8; ++i) Vt[c8 * 8 + i][kv] = vv[i];
    }
    __syncthreads();

    // S = Q K^T  (per wave: 16 x 64)
    f32x4 s[4] = {};
#pragma unroll
    for (int kf = 0; kf < 2; ++kf) {
#pragma unroll
      for (int j = 0; j < 4; ++j) {
        bf16x8 kb = *(const bf16x8*)&Kt[j * 16 + l15][kf * 32 + l4 * 8];
        s[j] = __builtin_amdgcn_mfma_f32_16x16x32_bf16(qf[kf], kb, s[j], 0, 0, 0);
      }
    }

    // scale + mask
    int mv[4];
#pragma unroll
    for (int j = 0; j < 4; ++j) mv[j] = mask[b * TT + kv0 + j * 16 + l15];
#pragma unroll
    for (int j = 0; j < 4; ++j)
#pragma unroll
      for (int i = 0; i < 4; ++i) {
        float sv = s[j][i] * 0.125f;
        s[j][i] = (mv[j] == 0) ? -1.0e9f : sv;
      }

    // tile row-max (rows live across the 16-lane group)
    float tm[4], mn[4], cor[4], em[4];
#pragma unroll
    for (int i = 0; i < 4; ++i) {
      tm[i] = fmaxf(fmaxf(s[0][i], s[1][i]), fmaxf(s[2][i], s[3][i]));
#pragma unroll
      for (int d = 1; d < 16; d <<= 1) tm[i] = fmaxf(tm[i], __shfl_xor(tm[i], d));
      mn[i] = fmaxf(m_r[i], tm[i]);
      cor[i] = __expf(m_r[i] - mn[i]);
      em[i] = __expf(-mn[i]);
    }

    // p = exp(s-m); sigmoid = p/(p+e^-m) (shares the exp); dump sigmoid
    float rs[4] = {0.f, 0.f, 0.f, 0.f};
#pragma unroll
    for (int j = 0; j < 4; ++j)
#pragma unroll
      for (int i = 0; i < 4; ++i) {
        float p = __expf(s[j][i] - mn[i]);
        float sg = p * __builtin_amdgcn_rcpf(p + em[i]);
        size_t soff = (((size_t)(b * HH + h)) * TT + (q0 + w * 16 + l4 * 4 + i)) * TT
                      + kv0 + j * 16 + l15;
        sig[soff] = sg;
        rs[i] += p;
        Pl[w][l4 * 4 + i][j * 16 + l15] = f2bf(p);
      }
#pragma unroll
    for (int i = 0; i < 4; ++i) {
#pragma unroll
      for (int d = 1; d < 16; d <<= 1) rs[i] += __shfl_xor(rs[i], d);
      l_r[i] = l_r[i] * cor[i] + rs[i];
      m_r[i] = mn[i];
    }
    // rescale O
#pragma unroll
    for (int n = 0; n < 4; ++n)
#pragma unroll
      for (int i = 0; i < 4; ++i) accO[n][i] *= cor[i];

    __syncthreads();  // Pl write -> read ordering (also gates next-iter staging)

    // O += P V : A-frag from Pl, B-frag from Vt (V^T so k runs contiguous)
    bf16x8 pa0 = *(const bf16x8*)&Pl[w][l15][l4 * 8];
    bf16x8 pa1 = *(const bf16x8*)&Pl[w][l15][32 + l4 * 8];
#pragma unroll
    for (int n = 0; n < 4; ++n) {
      bf16x8 vb0 = *(const bf16x8*)&Vt[n * 16 + l15][l4 * 8];
      bf16x8 vb1 = *(const bf16x8*)&Vt[n * 16 + l15][32 + l4 * 8];
      accO[n] = __builtin_amdgcn_mfma_f32_16x16x32_bf16(pa0, vb0, accO[n], 0, 0, 0);
      accO[n] = __builtin_amdgcn_mfma_f32_16x16x32_bf16(pa1, vb1, accO[n], 0, 0, 0);
    }
  }

  // x = O / l  -> ws (bf16), layout (b, q, h*64+d) so out-proj reads row-major
#pragma unroll
  for (int i = 0; i < 4; ++i) {
    float inv = __builtin_amdgcn_rcpf(l_r[i]);
#pragma unroll
    for (int n = 0; n < 4; ++n) {
      Xout[((size_t)b * TT + q0 + w * 16 + l4 * 4 + i) * DD + h * DKK + n * 16 + l15] =
          f2bf(accO[n][i] * inv);
    }
  }
}

// ---------------------------------------------------------------------------
extern "C" void kernel_launch(void* const* d_in, const int* in_sizes, int n_in,
                              void* d_out, int out_size, void* d_ws, size_t ws_size,
                              hipStream_t stream) {
  const float* query = (const float*)d_in[0];
  const float* key   = (const float*)d_in[1];
  const float* value = (const float*)d_in[2];
  const int*   mask  = (const int*)d_in[3];
  const float* Wq = (const float*)d_in[4];
  const float* bq = (const float*)d_in[5];
  const float* Wk = (const float*)d_in[6];
  const float* bk = (const float*)d_in[7];
  const float* Wv = (const float*)d_in[8];
  const float* bv = (const float*)d_in[9];
  const float* Wo = (const float*)d_in[10];
  const float* bo = (const float*)d_in[11];

  const size_t NTOK = (size_t)BB * TT * DD;  // 4M elements
  short* Qp = (short*)d_ws;
  short* Kp = Qp + NTOK;
  short* Vp = Kp + NTOK;
  short* Xx = Vp + NTOK;   // 32MB of ws used

  float* outp = (float*)d_out;
  float* sig  = outp + NTOK;

  ProjArgs pa;
  pa.A[0] = query; pa.A[1] = key; pa.A[2] = value;
  pa.W[0] = Wq; pa.W[1] = Wk; pa.W[2] = Wv;
  pa.bias[0] = bq; pa.bias[1] = bk; pa.bias[2] = bv;
  pa.C[0] = Qp; pa.C[1] = Kp; pa.C[2] = Vp;

  dim3 g1(64, 4, 3);   // M/128 x N/128 x {Q,K,V}
  proj_gemm_kernel<<<g1, 256, 0, stream>>>(pa);

  dim3 g2(TT / 64, HH, BB);
  attn_kernel<<<g2, 256, 0, stream>>>(Qp, Kp, Vp, mask, sig, Xx);

  dim3 g3(64, 4, 1);
  out_gemm_kernel<<<g3, 256, 0, stream>>>(Xx, Wo, bo, outp);
}